// Round 4
// baseline (1385.875 us; speedup 1.0000x reference)
//
#include <hip/hip_runtime.h>

#define FEATS 40960
#define ACC 512
#define NBATCH 4096
#define CAP 192
#define NTHR 256

// ws layout: [wt: FEATS*ACC f32][cnts: 2*NBATCH i32][idxs: 2*NBATCH*CAP i32]
#define WT_BYTES ((size_t)FEATS * ACC * 4)
#define CNT_BYTES ((size_t)2 * NBATCH * 4)

#define SCAN_UNITS (2 * NBATCH)                      // 8192
#define TR_UNITS ((FEATS / 64) * (ACC / 64))         // 5120

__device__ __forceinline__ float screlu_f(float v) {
  v = fminf(fmaxf(v, 0.0f), 1.0f);
  return v * v;
}

union __align__(16) ShMemA {
  float tile[64][65];                       // transpose tile (16.64 KB)
  struct { int cnt; int lidx[CAP]; } scan;  // scan compaction
};

// Phase-A kernel: blocks 0..8191 scan a (row,color) feature vector;
// blocks 8192..13311 transpose one 64x64 tile of ft_w into wt.
// Scans are dispatched first (the BW-bound stream); transposes ride the tail
// and leave wt freshly L3-resident for the MLP kernel.
__global__ __launch_bounds__(NTHR) void scan_and_transpose(
    const float* __restrict__ wfeat, const float* __restrict__ bfeat,
    const float* __restrict__ ftw,
    float* __restrict__ wt, int* __restrict__ cnts, int* __restrict__ idxs)
{
  __shared__ ShMemA sh;
  const int t = threadIdx.x;
  const int u = blockIdx.x;

  if (u < SCAN_UNITS) {
    const int row = u & (NBATCH - 1);
    const int color = u >> 12;
    if (t == 0) sh.scan.cnt = 0;
    __syncthreads();
    const float* feat = color ? bfeat : wfeat;
    const uint4* f4 = (const uint4*)(feat + (size_t)row * FEATS);
    for (int i = t; i < FEATS / 4; i += NTHR) {
      const uint4 a = f4[i];
      if (a.x | a.y | a.z | a.w) {
        if (a.x) { int p = atomicAdd(&sh.scan.cnt, 1); if (p < CAP) sh.scan.lidx[p] = 4 * i + 0; }
        if (a.y) { int p = atomicAdd(&sh.scan.cnt, 1); if (p < CAP) sh.scan.lidx[p] = 4 * i + 1; }
        if (a.z) { int p = atomicAdd(&sh.scan.cnt, 1); if (p < CAP) sh.scan.lidx[p] = 4 * i + 2; }
        if (a.w) { int p = atomicAdd(&sh.scan.cnt, 1); if (p < CAP) sh.scan.lidx[p] = 4 * i + 3; }
      }
    }
    __syncthreads();
    const int n = min(sh.scan.cnt, CAP);
    if (t == 0) cnts[u] = n;
    for (int i = t; i < n; i += NTHR) idxs[(size_t)u * CAP + i] = sh.scan.lidx[i];
  } else {
    const int v = u - SCAN_UNITS;
    const int f0 = (v % (FEATS / 64)) * 64;
    const int o0 = (v / (FEATS / 64)) * 64;
    const int tx = t & 63;
    const int ty = t >> 6;
#pragma unroll
    for (int i = 0; i < 16; ++i) {
      const int o = ty * 16 + i;
      sh.tile[o][tx] = ftw[(size_t)(o0 + o) * FEATS + (f0 + tx)];
    }
    __syncthreads();
#pragma unroll
    for (int i = 0; i < 16; ++i) {
      const int f = ty * 16 + i;
      wt[(size_t)(f0 + f) * ACC + (o0 + tx)] = sh.tile[tx][f];
    }
  }
}

// Per-row gather + tiny MLP. One block per batch row, 256 threads. (Proven in R2.)
__global__ __launch_bounds__(NTHR) void nnue_mlp(
    const int* __restrict__ cnts, const int* __restrict__ idxs,
    const unsigned char* __restrict__ stm8,
    const float* __restrict__ wt, const float* __restrict__ ftb,
    const float* __restrict__ l1w, const float* __restrict__ l1b,
    const float* __restrict__ l2w, const float* __restrict__ l2b,
    const float* __restrict__ ow, const float* __restrict__ ob,
    float* __restrict__ out)
{
  __shared__ int u8flag;
  __shared__ int widx[CAP], bidx[CAP];
  __shared__ __align__(16) float x[1024];
  __shared__ float part[8][32];
  __shared__ float v1[32];

  const int t = threadIdx.x;
  const int row = blockIdx.x;

  if (t == 0) u8flag = 0;
  __syncthreads();

  // stm storage-format probe: int32-encoded bools have zero bytes at 4k+1.
  if (stm8[4 * t + 1] != 0) u8flag = 1;

  const int nw = min(cnts[row], CAP);
  const int nb = min(cnts[NBATCH + row], CAP);
  for (int i = t; i < nw; i += NTHR) widx[i] = idxs[(size_t)row * CAP + i];
  for (int i = t; i < nb; i += NTHR) bidx[i] = idxs[(size_t)(NBATCH + row) * CAP + i];
  __syncthreads();

  // gather-accumulate transposed ft_w rows; thread owns acc elems 2t, 2t+1
  float accwx = 0.f, accwy = 0.f, accbx = 0.f, accby = 0.f;
  const float2* wt2 = (const float2*)wt;
  for (int i = 0; i < nw; ++i) {
    const float2 v = wt2[(size_t)widx[i] * (ACC / 2) + t];
    accwx += v.x; accwy += v.y;
  }
  for (int i = 0; i < nb; ++i) {
    const float2 v = wt2[(size_t)bidx[i] * (ACC / 2) + t];
    accbx += v.x; accby += v.y;
  }
  const float2 bias = ((const float2*)ftb)[t];
  accwx = screlu_f(accwx + bias.x); accwy = screlu_f(accwy + bias.y);
  accbx = screlu_f(accbx + bias.x); accby = screlu_f(accby + bias.y);

  // stm select into x[1024]: first half = stm ? black : white
  const int stm = (u8flag != 0) ? (int)stm8[row] : ((const int*)stm8)[row];
  const int woff = stm ? 512 : 0;
  const int boff = 512 - woff;
  x[woff + 2 * t]     = accwx;
  x[woff + 2 * t + 1] = accwy;
  x[boff + 2 * t]     = accbx;
  x[boff + 2 * t + 1] = accby;
  __syncthreads();

  // l1: 32 outputs x dot-1024; thread (o = t&31, chunk c = t>>5)
  const int o = t & 31, c = t >> 5;
  const float4* lw4 = (const float4*)(l1w + (size_t)o * 1024 + c * 128);
  const float4* x4  = (const float4*)(x) + c * 32;
  float s = 0.f;
#pragma unroll
  for (int i = 0; i < 32; ++i) {
    const float4 wv = lw4[i];
    const float4 xv = x4[i];
    s += wv.x * xv.x + wv.y * xv.y + wv.z * xv.z + wv.w * xv.w;
  }
  part[c][o] = s;
  __syncthreads();

  if (t < 32) {
    float r = l1b[t];
#pragma unroll
    for (int cc = 0; cc < 8; ++cc) r += part[cc][t];
    v1[t] = screlu_f(r);
  }
  __syncthreads();

  if (t < 32) {
    float r = l2b[t];
#pragma unroll
    for (int k = 0; k < 32; ++k) r += l2w[t * 32 + k] * v1[k];
    float res = screlu_f(r) * ow[t];
#pragma unroll
    for (int off = 16; off; off >>= 1) res += __shfl_down(res, off, 32);
    if (t == 0) out[row] = res + ob[0];
  }
}

extern "C" void kernel_launch(void* const* d_in, const int* in_sizes, int n_in,
                              void* d_out, int out_size, void* d_ws, size_t ws_size,
                              hipStream_t stream) {
  const float* wfeat = (const float*)d_in[0];
  const float* bfeat = (const float*)d_in[1];
  const unsigned char* stm = (const unsigned char*)d_in[2];
  const float* ftw = (const float*)d_in[3];
  const float* ftb = (const float*)d_in[4];
  const float* l1w = (const float*)d_in[5];
  const float* l1b = (const float*)d_in[6];
  const float* l2w = (const float*)d_in[7];
  const float* l2b = (const float*)d_in[8];
  const float* ow  = (const float*)d_in[9];
  const float* ob  = (const float*)d_in[10];
  float* out = (float*)d_out;

  float* wt   = (float*)d_ws;
  int*   cnts = (int*)((char*)d_ws + WT_BYTES);
  int*   idxs = (int*)((char*)d_ws + WT_BYTES + CNT_BYTES);

  scan_and_transpose<<<dim3(SCAN_UNITS + TR_UNITS), dim3(NTHR), 0, stream>>>(
      wfeat, bfeat, ftw, wt, cnts, idxs);
  nnue_mlp<<<dim3(NBATCH), dim3(NTHR), 0, stream>>>(
      cnts, idxs, stm, wt, ftb, l1w, l1b, l2w, l2b, ow, ob, out);
}

// Round 5
// 1367.207 us; speedup vs baseline: 1.0137x; 1.0137x over previous
//
#include <hip/hip_runtime.h>

#define FEATS 40960
#define ACC 512
#define NBATCH 4096
#define CAP 192
#define NTHR 256

// ws layout: [wt: FEATS*ACC bf16 (42MB)][cnts: 2*NBATCH i32][idxs: 2*NBATCH*CAP i32]
#define WT_BYTES ((size_t)FEATS * ACC * 2)
#define CNT_BYTES ((size_t)2 * NBATCH * 4)

#define TR_UNITS ((FEATS / 64) * (ACC / 64))  // 5120 (dispatch first)
#define SCAN_UNITS (2 * NBATCH)               // 8192

__device__ __forceinline__ float screlu_f(float v) {
  v = fminf(fmaxf(v, 0.0f), 1.0f);
  return v * v;
}

// bf16 round-to-nearest-even (weights are finite normals; no NaN handling needed)
__device__ __forceinline__ unsigned short f2bf(float x) {
  unsigned int u = __float_as_uint(x);
  u += 0x7fffu + ((u >> 16) & 1u);
  return (unsigned short)(u >> 16);
}

union __align__(16) ShMemA {
  float tile[64][65];                       // transpose tile (16.64 KB)
  struct { int cnt; int lidx[CAP]; } scan;  // scan compaction
};

// Blocks 0..TR_UNITS-1: transpose one 64x64 tile of ft_w into bf16 wt.
// Blocks TR_UNITS..: scan one (row,color) feature vector for nonzeros.
// Transposes dispatch first so they overlap the BW-bound scan stream.
__global__ __launch_bounds__(NTHR) void scan_and_transpose(
    const float* __restrict__ wfeat, const float* __restrict__ bfeat,
    const float* __restrict__ ftw,
    unsigned int* __restrict__ wtb, int* __restrict__ cnts, int* __restrict__ idxs)
{
  __shared__ ShMemA sh;
  const int t = threadIdx.x;
  const int u = blockIdx.x;

  if (u < TR_UNITS) {
    const int f0 = (u % (FEATS / 64)) * 64;
    const int o0 = (u / (FEATS / 64)) * 64;
    const int tx = t & 63;
    const int ty = t >> 6;
#pragma unroll
    for (int i = 0; i < 16; ++i) {
      const int o = ty * 16 + i;
      sh.tile[o][tx] = ftw[(size_t)(o0 + o) * FEATS + (f0 + tx)];
    }
    __syncthreads();
    // 256 threads = 8 f-rows x 32 o-pairs; uint (bf16x2) stores, 4B/lane.
    const int c = t & 31;   // o-pair
    const int fr = t >> 5;  // f row group
#pragma unroll
    for (int i = 0; i < 8; ++i) {
      const int f = i * 8 + fr;
      const unsigned int lo = f2bf(sh.tile[2 * c][f]);
      const unsigned int hi = f2bf(sh.tile[2 * c + 1][f]);
      wtb[((size_t)(f0 + f) * ACC + o0) / 2 + c] = lo | (hi << 16);
    }
  } else {
    const int su = u - TR_UNITS;
    const int row = su & (NBATCH - 1);
    const int color = su >> 12;
    if (t == 0) sh.scan.cnt = 0;
    __syncthreads();
    const float* feat = color ? bfeat : wfeat;
    const uint4* f4 = (const uint4*)(feat + (size_t)row * FEATS);
    for (int i = t; i < FEATS / 4; i += NTHR) {
      const uint4 a = f4[i];
      if (a.x | a.y | a.z | a.w) {
        if (a.x) { int p = atomicAdd(&sh.scan.cnt, 1); if (p < CAP) sh.scan.lidx[p] = 4 * i + 0; }
        if (a.y) { int p = atomicAdd(&sh.scan.cnt, 1); if (p < CAP) sh.scan.lidx[p] = 4 * i + 1; }
        if (a.z) { int p = atomicAdd(&sh.scan.cnt, 1); if (p < CAP) sh.scan.lidx[p] = 4 * i + 2; }
        if (a.w) { int p = atomicAdd(&sh.scan.cnt, 1); if (p < CAP) sh.scan.lidx[p] = 4 * i + 3; }
      }
    }
    __syncthreads();
    const int n = min(sh.scan.cnt, CAP);
    if (t == 0) cnts[su] = n;
    for (int i = t; i < n; i += NTHR) idxs[(size_t)su * CAP + i] = sh.scan.lidx[i];
  }
}

// Per-row gather (bf16 wt) + tiny MLP. One block per batch row, 256 threads.
__global__ __launch_bounds__(NTHR) void nnue_mlp(
    const int* __restrict__ cnts, const int* __restrict__ idxs,
    const unsigned char* __restrict__ stm8,
    const unsigned int* __restrict__ wtb, const float* __restrict__ ftb,
    const float* __restrict__ l1w, const float* __restrict__ l1b,
    const float* __restrict__ l2w, const float* __restrict__ l2b,
    const float* __restrict__ ow, const float* __restrict__ ob,
    float* __restrict__ out)
{
  __shared__ int u8flag;
  __shared__ int widx[CAP], bidx[CAP];
  __shared__ __align__(16) float x[1024];
  __shared__ float part[8][32];
  __shared__ float v1[32];

  const int t = threadIdx.x;
  const int row = blockIdx.x;

  if (t == 0) u8flag = 0;
  __syncthreads();

  // stm storage-format probe: int32-encoded bools have zero bytes at 4k+1.
  if (stm8[4 * t + 1] != 0) u8flag = 1;

  const int nw = min(cnts[row], CAP);
  const int nb = min(cnts[NBATCH + row], CAP);
  for (int i = t; i < nw; i += NTHR) widx[i] = idxs[(size_t)row * CAP + i];
  for (int i = t; i < nb; i += NTHR) bidx[i] = idxs[(size_t)(NBATCH + row) * CAP + i];
  __syncthreads();

  // gather-accumulate bf16 wt rows; thread owns acc elems 2t, 2t+1 (one uint/row)
  float accwx = 0.f, accwy = 0.f, accbx = 0.f, accby = 0.f;
#pragma unroll 4
  for (int i = 0; i < nw; ++i) {
    const unsigned int v = wtb[(size_t)widx[i] * (ACC / 2) + t];
    accwx += __uint_as_float(v << 16);
    accwy += __uint_as_float(v & 0xffff0000u);
  }
#pragma unroll 4
  for (int i = 0; i < nb; ++i) {
    const unsigned int v = wtb[(size_t)bidx[i] * (ACC / 2) + t];
    accbx += __uint_as_float(v << 16);
    accby += __uint_as_float(v & 0xffff0000u);
  }
  const float2 bias = ((const float2*)ftb)[t];
  accwx = screlu_f(accwx + bias.x); accwy = screlu_f(accwy + bias.y);
  accbx = screlu_f(accbx + bias.x); accby = screlu_f(accby + bias.y);

  // stm select into x[1024]: first half = stm ? black : white
  const int stm = (u8flag != 0) ? (int)stm8[row] : ((const int*)stm8)[row];
  const int woff = stm ? 512 : 0;
  const int boff = 512 - woff;
  x[woff + 2 * t]     = accwx;
  x[woff + 2 * t + 1] = accwy;
  x[boff + 2 * t]     = accbx;
  x[boff + 2 * t + 1] = accby;
  __syncthreads();

  // l1: 32 outputs x dot-1024; thread (o = t&31, chunk c = t>>5)
  const int o = t & 31, c = t >> 5;
  const float4* lw4 = (const float4*)(l1w + (size_t)o * 1024 + c * 128);
  const float4* x4  = (const float4*)(x) + c * 32;
  float s = 0.f;
#pragma unroll
  for (int i = 0; i < 32; ++i) {
    const float4 wv = lw4[i];
    const float4 xv = x4[i];
    s += wv.x * xv.x + wv.y * xv.y + wv.z * xv.z + wv.w * xv.w;
  }
  part[c][o] = s;
  __syncthreads();

  if (t < 32) {
    float r = l1b[t];
#pragma unroll
    for (int cc = 0; cc < 8; ++cc) r += part[cc][t];
    v1[t] = screlu_f(r);
  }
  __syncthreads();

  if (t < 32) {
    float r = l2b[t];
#pragma unroll
    for (int k = 0; k < 32; ++k) r += l2w[t * 32 + k] * v1[k];
    float res = screlu_f(r) * ow[t];
#pragma unroll
    for (int off = 16; off; off >>= 1) res += __shfl_down(res, off, 32);
    if (t == 0) out[row] = res + ob[0];
  }
}

extern "C" void kernel_launch(void* const* d_in, const int* in_sizes, int n_in,
                              void* d_out, int out_size, void* d_ws, size_t ws_size,
                              hipStream_t stream) {
  const float* wfeat = (const float*)d_in[0];
  const float* bfeat = (const float*)d_in[1];
  const unsigned char* stm = (const unsigned char*)d_in[2];
  const float* ftw = (const float*)d_in[3];
  const float* ftb = (const float*)d_in[4];
  const float* l1w = (const float*)d_in[5];
  const float* l1b = (const float*)d_in[6];
  const float* l2w = (const float*)d_in[7];
  const float* l2b = (const float*)d_in[8];
  const float* ow  = (const float*)d_in[9];
  const float* ob  = (const float*)d_in[10];
  float* out = (float*)d_out;

  unsigned int* wtb = (unsigned int*)d_ws;
  int* cnts = (int*)((char*)d_ws + WT_BYTES);
  int* idxs = (int*)((char*)d_ws + WT_BYTES + CNT_BYTES);

  scan_and_transpose<<<dim3(TR_UNITS + SCAN_UNITS), dim3(NTHR), 0, stream>>>(
      wfeat, bfeat, ftw, wtb, cnts, idxs);
  nnue_mlp<<<dim3(NBATCH), dim3(NTHR), 0, stream>>>(
      cnts, idxs, stm, wtb, ftb, l1w, l1b, l2w, l2b, ow, ob, out);
}